// Round 1
// baseline (2287.562 us; speedup 1.0000x reference)
//
#include <hip/hip_runtime.h>

// ---------------------------------------------------------------------------
// GCN encoder: out = GCNConv2( relu(GCNConv1(x)) )
// GCNConv(x) = scatter_add_{e:(s,d)} (xW)[s] * dinv[s]*dinv[d]  + (xW)[n]*dinv[n]^2 + b
// deg[n] = 1 + in-degree(n)  (self-loops), dinv = rsqrt(deg)
// ---------------------------------------------------------------------------

// edge_index may arrive as int64 (reference dtype) or int32 (harness contract).
// Detect: for int64, node ids < 2^31 => every odd 32-bit word of the array is 0.
__global__ void detect64_kernel(const int* __restrict__ ei, int* __restrict__ flag) {
    __shared__ int nz;
    if (threadIdx.x == 0) nz = 0;
    __syncthreads();
    if (ei[2 * threadIdx.x + 1] != 0) atomicOr(&nz, 1);
    __syncthreads();
    if (threadIdx.x == 0) *flag = (nz == 0) ? 1 : 0;
}

__device__ __forceinline__ int edge_id(const int* __restrict__ ei, int is64, long long pos) {
    // pos in [0, 2E): src at pos=e, dst at pos=E+e. int64 case: low dword holds value.
    return is64 ? ei[2 * pos] : ei[(int)pos];
}

__global__ void init_deg_kernel(float* __restrict__ deg, int N) {
    int n = blockIdx.x * blockDim.x + threadIdx.x;
    if (n < N) deg[n] = 1.0f;  // self-loop
}

__global__ void count_deg_kernel(const int* __restrict__ ei, const int* __restrict__ flag,
                                 float* __restrict__ deg, int E) {
    int e = blockIdx.x * blockDim.x + threadIdx.x;
    if (e >= E) return;
    int is64 = *flag;
    int d = edge_id(ei, is64, (long long)E + e);
    atomicAdd(&deg[d], 1.0f);
}

__global__ void dinv_kernel(float* __restrict__ deg, int N) {
    int n = blockIdx.x * blockDim.x + threadIdx.x;
    if (n < N) deg[n] = rsqrtf(deg[n]);   // deg >= 1 always
}

__global__ void norm_kernel(const int* __restrict__ ei, const int* __restrict__ flag,
                            const float* __restrict__ dinv, float* __restrict__ norm, int E) {
    int e = blockIdx.x * blockDim.x + threadIdx.x;
    if (e >= E) return;
    int is64 = *flag;
    int s = edge_id(ei, is64, e);
    int d = edge_id(ei, is64, (long long)E + e);
    norm[e] = dinv[s] * dinv[d];
}

// ---------------------------------------------------------------------------
// Simple fp32 tiled GEMM: C[M,N] = A[M,K] @ B[K,N].  N == BN (single col-block).
// ---------------------------------------------------------------------------
template <int BM, int BN, int BK, int TM, int TN>
__global__ void sgemm_kernel(const float* __restrict__ A, const float* __restrict__ B,
                             float* __restrict__ C, int M, int N, int K) {
    constexpr int THREADS = (BM / TM) * (BN / TN);
    __shared__ float As[BK][BM + 1];
    __shared__ float Bs[BK][BN];

    const int tid = threadIdx.x;
    const int tx = tid % (BN / TN);
    const int ty = tid / (BN / TN);
    const int row0 = blockIdx.y * BM;

    float acc[TM][TN] = {};

    constexpr int A_F4 = BM * BK / 4;
    constexpr int B_F4 = BK * BN / 4;

    for (int kt = 0; kt < K; kt += BK) {
        for (int i = tid; i < A_F4; i += THREADS) {
            int m  = i / (BK / 4);
            int k4 = (i % (BK / 4)) * 4;
            float4 v = make_float4(0.f, 0.f, 0.f, 0.f);
            int gr = row0 + m;
            if (gr < M) v = *(const float4*)&A[(long long)gr * K + kt + k4];
            As[k4 + 0][m] = v.x; As[k4 + 1][m] = v.y;
            As[k4 + 2][m] = v.z; As[k4 + 3][m] = v.w;
        }
        for (int i = tid; i < B_F4; i += THREADS) {
            int k  = i / (BN / 4);
            int n4 = (i % (BN / 4)) * 4;
            *(float4*)&Bs[k][n4] = *(const float4*)&B[(long long)(kt + k) * N + n4];
        }
        __syncthreads();

        for (int k = 0; k < BK; ++k) {
            float aR[TM], bR[TN];
#pragma unroll
            for (int i = 0; i < TM; ++i) aR[i] = As[k][ty * TM + i];
#pragma unroll
            for (int j = 0; j < TN; ++j) bR[j] = Bs[k][tx * TN + j];
#pragma unroll
            for (int i = 0; i < TM; ++i)
#pragma unroll
                for (int j = 0; j < TN; ++j) acc[i][j] = fmaf(aR[i], bR[j], acc[i][j]);
        }
        __syncthreads();
    }

#pragma unroll
    for (int i = 0; i < TM; ++i) {
        int gr = row0 + ty * TM + i;
        if (gr >= M) continue;
#pragma unroll
        for (int j = 0; j < TN; j += 4) {
            *(float4*)&C[(long long)gr * N + tx * TN + j] =
                make_float4(acc[i][j], acc[i][j + 1], acc[i][j + 2], acc[i][j + 3]);
        }
    }
}

// ---------------------------------------------------------------------------
// Edge scatter: out[dst] += h[src] * norm[e], one thread per (edge, float4)
// ---------------------------------------------------------------------------
template <int F>
__global__ void aggregate_kernel(const float* __restrict__ h, const int* __restrict__ ei,
                                 const int* __restrict__ flag, const float* __restrict__ norm,
                                 float* __restrict__ out, int E) {
    constexpr int CH = F / 4;
    long long task = (long long)blockIdx.x * blockDim.x + threadIdx.x;
    if (task >= (long long)E * CH) return;
    int e = (int)(task / CH);
    int c = (int)(task % CH);
    int is64 = *flag;
    int s = edge_id(ei, is64, e);
    int d = edge_id(ei, is64, (long long)E + e);
    float w = norm[e];
    float4 v = *(const float4*)&h[(long long)s * F + c * 4];
    float* o = &out[(long long)d * F + c * 4];
    atomicAdd(o + 0, v.x * w);
    atomicAdd(o + 1, v.y * w);
    atomicAdd(o + 2, v.z * w);
    atomicAdd(o + 3, v.w * w);
}

// epilogue layer 1: agg = relu(agg + h*dinv^2 + b)
__global__ void finish1_kernel(float* __restrict__ agg, const float* __restrict__ h,
                               const float* __restrict__ dinv, const float* __restrict__ b,
                               int F) {
    int n = blockIdx.x;
    int f = threadIdx.x;
    float di = dinv[n];
    long long i = (long long)n * F + f;
    float v = agg[i] + h[i] * di * di + b[f];
    agg[i] = fmaxf(v, 0.f);
}

// epilogue layer 2: out += h*dinv^2 + b   (no relu)
__global__ void finish2_kernel(float* __restrict__ out, const float* __restrict__ h,
                               const float* __restrict__ dinv, const float* __restrict__ b,
                               int F) {
    int n = blockIdx.x;
    int f = threadIdx.x;
    float di = dinv[n];
    long long i = (long long)n * F + f;
    out[i] = out[i] + h[i] * di * di + b[f];
}

extern "C" void kernel_launch(void* const* d_in, const int* in_sizes, int n_in,
                              void* d_out, int out_size, void* d_ws, size_t ws_size,
                              hipStream_t stream) {
    const float* x  = (const float*)d_in[0];
    const int*   ei = (const int*)d_in[1];
    const float* W1 = (const float*)d_in[2];
    const float* b1 = (const float*)d_in[3];
    const float* W2 = (const float*)d_in[4];
    const float* b2 = (const float*)d_in[5];
    float* out = (float*)d_out;

    const int IN_CH = 256, HID = 128, OUT = 64;
    const int N = in_sizes[0] / IN_CH;     // 50000
    const int E = in_sizes[1] / 2;         // 800000

    // workspace carve-up (256B aligned)
    char* w = (char*)d_ws;
    size_t off = 0;
    auto alloc = [&](size_t bytes) { void* p = w + off; off = (off + bytes + 255) & ~(size_t)255; return p; };
    float* deg  = (float*)alloc((size_t)N * 4);            // becomes dinv in-place
    int*   flag = (int*)alloc(256);
    float* norm = (float*)alloc((size_t)E * 4);
    float* h1   = (float*)alloc((size_t)N * HID * 4);      // reused as h2
    float* agg1 = (float*)alloc((size_t)N * HID * 4);
    float* h2   = h1;

    // zero accumulation targets (d_out / d_ws are poisoned before every call)
    hipMemsetAsync(agg1, 0, (size_t)N * HID * 4, stream);
    hipMemsetAsync(out,  0, (size_t)N * OUT * 4, stream);

    const int T = 256;
    detect64_kernel<<<1, 256, 0, stream>>>(ei, flag);
    init_deg_kernel<<<(N + T - 1) / T, T, 0, stream>>>(deg, N);
    count_deg_kernel<<<(E + T - 1) / T, T, 0, stream>>>(ei, flag, deg, E);
    dinv_kernel<<<(N + T - 1) / T, T, 0, stream>>>(deg, N);
    norm_kernel<<<(E + T - 1) / T, T, 0, stream>>>(ei, flag, deg, norm, E);

    // GEMM1: h1[N,128] = x[N,256] @ W1[256,128]
    {
        dim3 grid(1, (N + 63) / 64);
        sgemm_kernel<64, 128, 32, 4, 8><<<grid, 256, 0, stream>>>(x, W1, h1, N, HID, IN_CH);
    }
    // aggregate layer 1 into agg1
    {
        long long tasks = (long long)E * (HID / 4);
        int blocks = (int)((tasks + T - 1) / T);
        aggregate_kernel<128><<<blocks, T, 0, stream>>>(h1, ei, flag, norm, agg1, E);
    }
    finish1_kernel<<<N, HID, 0, stream>>>(agg1, h1, deg, b1, HID);

    // GEMM2: h2[N,64] = agg1[N,128] @ W2[128,64]
    {
        dim3 grid(1, (N + 63) / 64);
        sgemm_kernel<64, 64, 32, 4, 4><<<grid, 256, 0, stream>>>(agg1, W2, h2, N, OUT, HID);
    }
    // aggregate layer 2 directly into out
    {
        long long tasks = (long long)E * (OUT / 4);
        int blocks = (int)((tasks + T - 1) / T);
        aggregate_kernel<64><<<blocks, T, 0, stream>>>(h2, ei, flag, norm, out, E);
    }
    finish2_kernel<<<N, OUT, 0, stream>>>(out, h2, deg, b2, OUT);
}

// Round 2
// 490.208 us; speedup vs baseline: 4.6665x; 4.6665x over previous
//
#include <hip/hip_runtime.h>

// ---------------------------------------------------------------------------
// GCN encoder: out = GCNConv2( relu(GCNConv1(x)) )
// Strategy: per-call CSR build over incoming edges (count/scan/scatter),
// then atomic-free gather aggregation fused with self-loop + bias (+ReLU).
// ---------------------------------------------------------------------------

// edge_index may arrive as int64 (reference dtype) or int32 (harness contract).
// Detect: for int64, node ids < 2^31 => every odd 32-bit word is 0.
__global__ void detect64_kernel(const int* __restrict__ ei, int* __restrict__ flag) {
    __shared__ int nz;
    if (threadIdx.x == 0) nz = 0;
    __syncthreads();
    if (ei[2 * threadIdx.x + 1] != 0) atomicOr(&nz, 1);
    __syncthreads();
    if (threadIdx.x == 0) *flag = (nz == 0) ? 1 : 0;
}

__device__ __forceinline__ int edge_id(const int* __restrict__ ei, int is64, long long pos) {
    return is64 ? ei[2 * pos] : ei[(int)pos];
}

// count in-degree (int) per dst
__global__ void count_deg_kernel(const int* __restrict__ ei, const int* __restrict__ flag,
                                 int* __restrict__ degi, int E) {
    int e = blockIdx.x * blockDim.x + threadIdx.x;
    if (e >= E) return;
    int is64 = *flag;
    int d = edge_id(ei, is64, (long long)E + e);
    atomicAdd(&degi[d], 1);
}

// dinv[n] = rsqrt(1 + in_degree[n])
__global__ void dinv_kernel(const int* __restrict__ degi, float* __restrict__ dinv, int N) {
    int n = blockIdx.x * blockDim.x + threadIdx.x;
    if (n < N) dinv[n] = rsqrtf(1.0f + (float)degi[n]);
}

// single-block exclusive scan of degi[N] -> off[N+1]
__global__ void scan_kernel(const int* __restrict__ degi, int* __restrict__ off, int N) {
    __shared__ int partial[1024];
    const int tid = threadIdx.x;
    const int chunk = (N + 1023) / 1024;
    const int start = tid * chunk;
    int sum = 0;
    for (int i = 0; i < chunk; ++i) {
        int idx = start + i;
        if (idx < N) sum += degi[idx];
    }
    partial[tid] = sum;
    __syncthreads();
    // Hillis-Steele inclusive scan over 1024 partials
    for (int s = 1; s < 1024; s <<= 1) {
        int v = (tid >= s) ? partial[tid - s] : 0;
        __syncthreads();
        partial[tid] += v;
        __syncthreads();
    }
    int base = (tid == 0) ? 0 : partial[tid - 1];
    for (int i = 0; i < chunk; ++i) {
        int idx = start + i;
        if (idx < N) { off[idx] = base; base += degi[idx]; }
    }
    if (tid == 1023) off[N] = partial[1023];
}

// scatter edges into CSR: csr[pos] = {src, w=dinv[src]*dinv[dst]}
__global__ void scatter_kernel(const int* __restrict__ ei, const int* __restrict__ flag,
                               const int* __restrict__ off, int* __restrict__ cursor,
                               const float* __restrict__ dinv, int2* __restrict__ csr, int E) {
    int e = blockIdx.x * blockDim.x + threadIdx.x;
    if (e >= E) return;
    int is64 = *flag;
    int s = edge_id(ei, is64, e);
    int d = edge_id(ei, is64, (long long)E + e);
    float w = dinv[s] * dinv[d];
    int pos = off[d] + atomicAdd(&cursor[d], 1);
    csr[pos] = make_int2(s, __float_as_int(w));
}

// ---------------------------------------------------------------------------
// Gather aggregation: per node n, acc[t] = h[n][t]*dinv[n]^2 + sum_e h[src][t]*w
// then + bias (+relu). Block = 256 threads = (256/F) nodes; each wave is
// uniform within one node (F=128: 2 waves/node; F=64: 1 wave/node).
// ---------------------------------------------------------------------------
template <int F, int RELU>
__global__ void gather_kernel(const float* __restrict__ h, const int2* __restrict__ csr,
                              const int* __restrict__ off, const float* __restrict__ dinv,
                              const float* __restrict__ bias, float* __restrict__ out, int N) {
    constexpr int NPB = 256 / F;
    const int local = threadIdx.x / F;
    const int t = threadIdx.x % F;
    const int n = blockIdx.x * NPB + local;
    if (n >= N) return;
    const float di = dinv[n];
    float acc = h[(long long)n * F + t] * di * di;
    int j = off[n];
    const int end = off[n + 1];
    for (; j + 1 < end; j += 2) {
        int2 a = csr[j];
        int2 b = csr[j + 1];
        float va = h[(long long)a.x * F + t];
        float vb = h[(long long)b.x * F + t];
        acc = fmaf(va, __int_as_float(a.y), acc);
        acc = fmaf(vb, __int_as_float(b.y), acc);
    }
    if (j < end) {
        int2 a = csr[j];
        acc = fmaf(h[(long long)a.x * F + t], __int_as_float(a.y), acc);
    }
    acc += bias[t];
    if (RELU) acc = fmaxf(acc, 0.f);
    out[(long long)n * F + t] = acc;
}

// ---------------------------------------------------------------------------
// Simple fp32 tiled GEMM: C[M,N] = A[M,K] @ B[K,N].  N == BN (single col-block).
// ---------------------------------------------------------------------------
template <int BM, int BN, int BK, int TM, int TN>
__global__ void sgemm_kernel(const float* __restrict__ A, const float* __restrict__ B,
                             float* __restrict__ C, int M, int N, int K) {
    constexpr int THREADS = (BM / TM) * (BN / TN);
    __shared__ float As[BK][BM + 1];
    __shared__ float Bs[BK][BN];

    const int tid = threadIdx.x;
    const int tx = tid % (BN / TN);
    const int ty = tid / (BN / TN);
    const int row0 = blockIdx.y * BM;

    float acc[TM][TN] = {};

    constexpr int A_F4 = BM * BK / 4;
    constexpr int B_F4 = BK * BN / 4;

    for (int kt = 0; kt < K; kt += BK) {
        for (int i = tid; i < A_F4; i += THREADS) {
            int m  = i / (BK / 4);
            int k4 = (i % (BK / 4)) * 4;
            float4 v = make_float4(0.f, 0.f, 0.f, 0.f);
            int gr = row0 + m;
            if (gr < M) v = *(const float4*)&A[(long long)gr * K + kt + k4];
            As[k4 + 0][m] = v.x; As[k4 + 1][m] = v.y;
            As[k4 + 2][m] = v.z; As[k4 + 3][m] = v.w;
        }
        for (int i = tid; i < B_F4; i += THREADS) {
            int k  = i / (BN / 4);
            int n4 = (i % (BN / 4)) * 4;
            *(float4*)&Bs[k][n4] = *(const float4*)&B[(long long)(kt + k) * N + n4];
        }
        __syncthreads();

        for (int k = 0; k < BK; ++k) {
            float aR[TM], bR[TN];
#pragma unroll
            for (int i = 0; i < TM; ++i) aR[i] = As[k][ty * TM + i];
#pragma unroll
            for (int j = 0; j < TN; ++j) bR[j] = Bs[k][tx * TN + j];
#pragma unroll
            for (int i = 0; i < TM; ++i)
#pragma unroll
                for (int j = 0; j < TN; ++j) acc[i][j] = fmaf(aR[i], bR[j], acc[i][j]);
        }
        __syncthreads();
    }

#pragma unroll
    for (int i = 0; i < TM; ++i) {
        int gr = row0 + ty * TM + i;
        if (gr >= M) continue;
#pragma unroll
        for (int j = 0; j < TN; j += 4) {
            *(float4*)&C[(long long)gr * N + tx * TN + j] =
                make_float4(acc[i][j], acc[i][j + 1], acc[i][j + 2], acc[i][j + 3]);
        }
    }
}

extern "C" void kernel_launch(void* const* d_in, const int* in_sizes, int n_in,
                              void* d_out, int out_size, void* d_ws, size_t ws_size,
                              hipStream_t stream) {
    const float* x  = (const float*)d_in[0];
    const int*   ei = (const int*)d_in[1];
    const float* W1 = (const float*)d_in[2];
    const float* b1 = (const float*)d_in[3];
    const float* W2 = (const float*)d_in[4];
    const float* b2 = (const float*)d_in[5];
    float* out = (float*)d_out;

    const int IN_CH = 256, HID = 128, OUT = 64;
    const int N = in_sizes[0] / IN_CH;     // 50000
    const int E = in_sizes[1] / 2;         // 800000

    // workspace carve-up (256B aligned)
    char* w = (char*)d_ws;
    size_t off_b = 0;
    auto alloc = [&](size_t bytes) { void* p = w + off_b; off_b = (off_b + bytes + 255) & ~(size_t)255; return p; };
    int*   flag   = (int*)alloc(256);
    int*   degi   = (int*)alloc((size_t)N * 4);
    int*   offs   = (int*)alloc((size_t)(N + 1) * 4);
    int*   cursor = (int*)alloc((size_t)N * 4);
    float* dinv   = (float*)alloc((size_t)N * 4);
    int2*  csr    = (int2*)alloc((size_t)E * 8);
    float* h1     = (float*)alloc((size_t)N * HID * 4);    // reused as h2
    float* agg1   = (float*)alloc((size_t)N * HID * 4);
    float* h2     = h1;

    hipMemsetAsync(degi,   0, (size_t)N * 4, stream);
    hipMemsetAsync(cursor, 0, (size_t)N * 4, stream);

    const int T = 256;
    detect64_kernel<<<1, 256, 0, stream>>>(ei, flag);
    count_deg_kernel<<<(E + T - 1) / T, T, 0, stream>>>(ei, flag, degi, E);
    dinv_kernel<<<(N + T - 1) / T, T, 0, stream>>>(degi, dinv, N);
    scan_kernel<<<1, 1024, 0, stream>>>(degi, offs, N);
    scatter_kernel<<<(E + T - 1) / T, T, 0, stream>>>(ei, flag, offs, cursor, dinv, csr, E);

    // GEMM1: h1[N,128] = x[N,256] @ W1[256,128]
    {
        dim3 grid(1, (N + 63) / 64);
        sgemm_kernel<64, 128, 32, 4, 8><<<grid, 256, 0, stream>>>(x, W1, h1, N, HID, IN_CH);
    }
    // layer-1 aggregation (gather, fused self-loop + bias + relu) -> agg1
    {
        int blocks = (N * 128 + 255) / 256;
        gather_kernel<128, 1><<<blocks, 256, 0, stream>>>(h1, csr, offs, dinv, b1, agg1, N);
    }
    // GEMM2: h2[N,64] = agg1[N,128] @ W2[128,64]
    {
        dim3 grid(1, (N + 63) / 64);
        sgemm_kernel<64, 64, 32, 4, 4><<<grid, 256, 0, stream>>>(agg1, W2, h2, N, OUT, HID);
    }
    // layer-2 aggregation (gather, fused self-loop + bias) -> out
    {
        int blocks = (N * 64 + 255) / 256;
        gather_kernel<64, 0><<<blocks, 256, 0, stream>>>(h2, csr, offs, dinv, b2, out, N);
    }
}

// Round 3
// 361.348 us; speedup vs baseline: 6.3306x; 1.3566x over previous
//
#include <hip/hip_runtime.h>

// ---------------------------------------------------------------------------
// GCN encoder: out = GCNConv2( relu(GCNConv1(x)) )
// R2: float4 gather, split-bf16 MFMA GEMMs, multi-block scan.
// ---------------------------------------------------------------------------

typedef __attribute__((ext_vector_type(8))) short short8;
typedef __attribute__((ext_vector_type(4))) float floatx4;

// edge_index may arrive as int64 (reference dtype) or int32 (harness contract).
__global__ void detect64_kernel(const int* __restrict__ ei, int* __restrict__ flag) {
    __shared__ int nz;
    if (threadIdx.x == 0) nz = 0;
    __syncthreads();
    if (ei[2 * threadIdx.x + 1] != 0) atomicOr(&nz, 1);
    __syncthreads();
    if (threadIdx.x == 0) *flag = (nz == 0) ? 1 : 0;
}

__device__ __forceinline__ int edge_id(const int* __restrict__ ei, int is64, long long pos) {
    return is64 ? ei[2 * pos] : ei[(int)pos];
}

__global__ void count_deg_kernel(const int* __restrict__ ei, const int* __restrict__ flag,
                                 int* __restrict__ degi, int E) {
    int e = blockIdx.x * blockDim.x + threadIdx.x;
    if (e >= E) return;
    int is64 = *flag;
    int d = edge_id(ei, is64, (long long)E + e);
    atomicAdd(&degi[d], 1);
}

__global__ void dinv_kernel(const int* __restrict__ degi, float* __restrict__ dinv, int N) {
    int n = blockIdx.x * blockDim.x + threadIdx.x;
    if (n < N) dinv[n] = rsqrtf(1.0f + (float)degi[n]);
}

// ---------------- multi-block exclusive scan: degi[N] -> offs[N+1] ----------
__global__ void blocksum_kernel(const int* __restrict__ degi, int* __restrict__ bsum, int N) {
    __shared__ int sm[256];
    int t = threadIdx.x;
    int idx = blockIdx.x * 256 + t;
    sm[t] = (idx < N) ? degi[idx] : 0;
    __syncthreads();
    for (int s = 128; s > 0; s >>= 1) {
        if (t < s) sm[t] += sm[t + s];
        __syncthreads();
    }
    if (t == 0) bsum[blockIdx.x] = sm[0];
}

__global__ void scanb_kernel(int* __restrict__ bsum, int nb) {
    __shared__ int sm[256];
    int t = threadIdx.x;
    int v = (t < nb) ? bsum[t] : 0;
    sm[t] = v;
    __syncthreads();
    for (int s = 1; s < 256; s <<= 1) {
        int u = (t >= s) ? sm[t - s] : 0;
        __syncthreads();
        sm[t] += u;
        __syncthreads();
    }
    if (t < nb) bsum[t] = sm[t] - v;   // exclusive
}

__global__ void writeoffs_kernel(const int* __restrict__ degi, const int* __restrict__ bsum,
                                 int* __restrict__ offs, int N) {
    __shared__ int sm[256];
    int t = threadIdx.x;
    int idx = blockIdx.x * 256 + t;
    int v = (idx < N) ? degi[idx] : 0;
    sm[t] = v;
    __syncthreads();
    for (int s = 1; s < 256; s <<= 1) {
        int u = (t >= s) ? sm[t - s] : 0;
        __syncthreads();
        sm[t] += u;
        __syncthreads();
    }
    int incl = sm[t];
    int base = bsum[blockIdx.x];
    if (idx < N) offs[idx] = base + incl - v;
    if (idx == N - 1) offs[N] = base + incl;
}

// scatter edges into CSR: csr[pos] = {src, w=dinv[src]*dinv[dst]}
__global__ void scatter_kernel(const int* __restrict__ ei, const int* __restrict__ flag,
                               const int* __restrict__ offs, int* __restrict__ cursor,
                               const float* __restrict__ dinv, int2* __restrict__ csr, int E) {
    int e = blockIdx.x * blockDim.x + threadIdx.x;
    if (e >= E) return;
    int is64 = *flag;
    int s = edge_id(ei, is64, e);
    int d = edge_id(ei, is64, (long long)E + e);
    float w = dinv[s] * dinv[d];
    int pos = offs[d] + atomicAdd(&cursor[d], 1);
    csr[pos] = make_int2(s, __float_as_int(w));
}

// ---------------------------------------------------------------------------
// Weight pre-transform: W[K][Nc] fp32 -> Wh_t/Wl_t [Nc][K] bf16 (split hi/lo)
// ---------------------------------------------------------------------------
__device__ __forceinline__ unsigned short bf16_rne(float x) {
    unsigned u = __float_as_uint(x);
    return (unsigned short)((u + 0x7fff + ((u >> 16) & 1)) >> 16);
}

__global__ void convW_kernel(const float* __restrict__ W, unsigned short* __restrict__ Ht,
                             unsigned short* __restrict__ Lt, int K, int Nc) {
    int idx = blockIdx.x * blockDim.x + threadIdx.x;
    if (idx >= K * Nc) return;
    int k = idx / Nc, n = idx % Nc;
    float a = W[idx];
    unsigned u = __float_as_uint(a);
    unsigned short hi = (unsigned short)(u >> 16);          // truncation
    float hf = __uint_as_float(u & 0xffff0000u);
    unsigned short lo = bf16_rne(a - hf);
    Ht[(long long)n * K + k] = hi;
    Lt[(long long)n * K + k] = lo;
}

// ---------------------------------------------------------------------------
// Split-bf16 MFMA GEMM: C[M,NCOL] = A[M,K]fp32 @ B[K,NCOL]fp32
// B given pre-transposed/split as Bh,Bl [NCOL][K] bf16.
// Block = 4 waves, each wave computes a 16 x NCOL stripe. No LDS.
// ---------------------------------------------------------------------------
template <int NCOL, int K>
__launch_bounds__(256)
__global__ void mfma_gemm_kernel(const float* __restrict__ A,
                                 const unsigned short* __restrict__ Bh,
                                 const unsigned short* __restrict__ Bl,
                                 float* __restrict__ C, int M) {
    constexpr int NCB = NCOL / 16;
    const int wave = threadIdx.x >> 6;
    const int lane = threadIdx.x & 63;
    const int n15 = lane & 15;
    const int q = lane >> 4;            // 0..3
    const int row = blockIdx.x * 64 + wave * 16 + n15;       // A row this lane reads
    const int arow = (row < M) ? row : (M - 1);

    floatx4 acc[NCB];
#pragma unroll
    for (int i = 0; i < NCB; ++i) acc[i] = (floatx4){0.f, 0.f, 0.f, 0.f};

#pragma unroll
    for (int kc = 0; kc < K; kc += 32) {
        // A fragment: 8 fp32 at A[arow][kc + q*8 ...]
        const float4* pA = (const float4*)&A[(long long)arow * K + kc + q * 8];
        float4 a0 = pA[0];
        float4 a1 = pA[1];
        float av[8] = {a0.x, a0.y, a0.z, a0.w, a1.x, a1.y, a1.z, a1.w};
        short8 ah, al;
#pragma unroll
        for (int j = 0; j < 8; ++j) {
            unsigned u = __float_as_uint(av[j]);
            ah[j] = (short)(u >> 16);
            float hf = __uint_as_float(u & 0xffff0000u);
            al[j] = (short)bf16_rne(av[j] - hf);
        }
#pragma unroll
        for (int cb = 0; cb < NCB; ++cb) {
            long long boff = (long long)(cb * 16 + n15) * K + kc + q * 8;
            short8 bh = *(const short8*)&Bh[boff];
            short8 bl = *(const short8*)&Bl[boff];
            acc[cb] = __builtin_amdgcn_mfma_f32_16x16x32_bf16(ah, bh, acc[cb], 0, 0, 0);
            acc[cb] = __builtin_amdgcn_mfma_f32_16x16x32_bf16(al, bh, acc[cb], 0, 0, 0);
            acc[cb] = __builtin_amdgcn_mfma_f32_16x16x32_bf16(ah, bl, acc[cb], 0, 0, 0);
        }
    }

    // C/D layout: col = lane&15 (+cb*16), row-in-tile = q*4 + reg
#pragma unroll
    for (int cb = 0; cb < NCB; ++cb) {
        int col = cb * 16 + n15;
#pragma unroll
        for (int r = 0; r < 4; ++r) {
            int gr = blockIdx.x * 64 + wave * 16 + q * 4 + r;
            if (gr < M) C[(long long)gr * NCOL + col] = acc[cb][r];
        }
    }
}

// ---------------------------------------------------------------------------
// Gather aggregation, float4 per lane:
// out[n][:] = (h[n]*dinv[n]^2 + sum_e h[src]*w) + bias (, relu)
// ---------------------------------------------------------------------------
template <int F, int RELU>
__launch_bounds__(256)
__global__ void gather4_kernel(const float* __restrict__ h, const int2* __restrict__ csr,
                               const int* __restrict__ offs, const float* __restrict__ dinv,
                               const float* __restrict__ bias, float* __restrict__ out, int N) {
    constexpr int L = F / 4;            // lanes per node
    constexpr int NPB = 256 / L;        // nodes per block
    const int n = blockIdx.x * NPB + threadIdx.x / L;
    const int c4 = (threadIdx.x % L) * 4;
    if (n >= N) return;
    const float di = dinv[n];
    float4 acc = *(const float4*)&h[(long long)n * F + c4];
    float sd = di * di;
    acc.x *= sd; acc.y *= sd; acc.z *= sd; acc.w *= sd;

    int j = offs[n];
    const int end = offs[n + 1];
    for (; j + 3 < end; j += 4) {
        int2 e0 = csr[j], e1 = csr[j + 1], e2 = csr[j + 2], e3 = csr[j + 3];
        float4 v0 = *(const float4*)&h[(long long)e0.x * F + c4];
        float4 v1 = *(const float4*)&h[(long long)e1.x * F + c4];
        float4 v2 = *(const float4*)&h[(long long)e2.x * F + c4];
        float4 v3 = *(const float4*)&h[(long long)e3.x * F + c4];
        float w0 = __int_as_float(e0.y), w1 = __int_as_float(e1.y);
        float w2 = __int_as_float(e2.y), w3 = __int_as_float(e3.y);
        acc.x = fmaf(v0.x, w0, acc.x); acc.y = fmaf(v0.y, w0, acc.y);
        acc.z = fmaf(v0.z, w0, acc.z); acc.w = fmaf(v0.w, w0, acc.w);
        acc.x = fmaf(v1.x, w1, acc.x); acc.y = fmaf(v1.y, w1, acc.y);
        acc.z = fmaf(v1.z, w1, acc.z); acc.w = fmaf(v1.w, w1, acc.w);
        acc.x = fmaf(v2.x, w2, acc.x); acc.y = fmaf(v2.y, w2, acc.y);
        acc.z = fmaf(v2.z, w2, acc.z); acc.w = fmaf(v2.w, w2, acc.w);
        acc.x = fmaf(v3.x, w3, acc.x); acc.y = fmaf(v3.y, w3, acc.y);
        acc.z = fmaf(v3.z, w3, acc.z); acc.w = fmaf(v3.w, w3, acc.w);
    }
    for (; j < end; ++j) {
        int2 e = csr[j];
        float w = __int_as_float(e.y);
        float4 v = *(const float4*)&h[(long long)e.x * F + c4];
        acc.x = fmaf(v.x, w, acc.x); acc.y = fmaf(v.y, w, acc.y);
        acc.z = fmaf(v.z, w, acc.z); acc.w = fmaf(v.w, w, acc.w);
    }
    float4 b = *(const float4*)&bias[c4];
    acc.x += b.x; acc.y += b.y; acc.z += b.z; acc.w += b.w;
    if (RELU) {
        acc.x = fmaxf(acc.x, 0.f); acc.y = fmaxf(acc.y, 0.f);
        acc.z = fmaxf(acc.z, 0.f); acc.w = fmaxf(acc.w, 0.f);
    }
    *(float4*)&out[(long long)n * F + c4] = acc;
}

extern "C" void kernel_launch(void* const* d_in, const int* in_sizes, int n_in,
                              void* d_out, int out_size, void* d_ws, size_t ws_size,
                              hipStream_t stream) {
    const float* x  = (const float*)d_in[0];
    const int*   ei = (const int*)d_in[1];
    const float* W1 = (const float*)d_in[2];
    const float* b1 = (const float*)d_in[3];
    const float* W2 = (const float*)d_in[4];
    const float* b2 = (const float*)d_in[5];
    float* out = (float*)d_out;

    const int IN_CH = 256, HID = 128, OUT = 64;
    const int N = in_sizes[0] / IN_CH;     // 50000
    const int E = in_sizes[1] / 2;         // 800000

    char* w = (char*)d_ws;
    size_t off_b = 0;
    auto alloc = [&](size_t bytes) { void* p = w + off_b; off_b = (off_b + bytes + 255) & ~(size_t)255; return p; };
    int*   flag   = (int*)alloc(256);
    int*   degi   = (int*)alloc((size_t)N * 4);
    int*   offs   = (int*)alloc((size_t)(N + 1) * 4);
    int*   cursor = (int*)alloc((size_t)N * 4);
    float* dinv   = (float*)alloc((size_t)N * 4);
    int*   bsum   = (int*)alloc(256 * 4);
    int2*  csr    = (int2*)alloc((size_t)E * 8);
    unsigned short* W1h = (unsigned short*)alloc((size_t)IN_CH * HID * 2);
    unsigned short* W1l = (unsigned short*)alloc((size_t)IN_CH * HID * 2);
    unsigned short* W2h = (unsigned short*)alloc((size_t)HID * OUT * 2);
    unsigned short* W2l = (unsigned short*)alloc((size_t)HID * OUT * 2);
    float* h1     = (float*)alloc((size_t)N * HID * 4);    // reused as h2
    float* agg1   = (float*)alloc((size_t)N * HID * 4);
    float* h2     = h1;

    hipMemsetAsync(degi,   0, (size_t)N * 4, stream);
    hipMemsetAsync(cursor, 0, (size_t)N * 4, stream);

    const int T = 256;
    const int nb = (N + 255) / 256;        // 196 blocks (<=256)
    detect64_kernel<<<1, 256, 0, stream>>>(ei, flag);
    count_deg_kernel<<<(E + T - 1) / T, T, 0, stream>>>(ei, flag, degi, E);
    dinv_kernel<<<(N + T - 1) / T, T, 0, stream>>>(degi, dinv, N);
    blocksum_kernel<<<nb, 256, 0, stream>>>(degi, bsum, N);
    scanb_kernel<<<1, 256, 0, stream>>>(bsum, nb);
    writeoffs_kernel<<<nb, 256, 0, stream>>>(degi, bsum, offs, N);
    scatter_kernel<<<(E + T - 1) / T, T, 0, stream>>>(ei, flag, offs, cursor, dinv, csr, E);

    convW_kernel<<<(IN_CH * HID + T - 1) / T, T, 0, stream>>>(W1, W1h, W1l, IN_CH, HID);
    convW_kernel<<<(HID * OUT + T - 1) / T, T, 0, stream>>>(W2, W2h, W2l, HID, OUT);

    // GEMM1: h1[N,128] = x[N,256] @ W1
    mfma_gemm_kernel<128, 256><<<(N + 63) / 64, 256, 0, stream>>>(x, W1h, W1l, h1, N);
    // layer-1 aggregation (gather, fused self-loop + bias + relu) -> agg1
    gather4_kernel<128, 1><<<(N + 7) / 8, 256, 0, stream>>>(h1, csr, offs, dinv, b1, agg1, N);
    // GEMM2: h2[N,64] = agg1[N,128] @ W2
    mfma_gemm_kernel<64, 128><<<(N + 63) / 64, 256, 0, stream>>>(agg1, W2h, W2l, h2, N);
    // layer-2 aggregation (gather, fused self-loop + bias) -> out
    gather4_kernel<64, 0><<<(N + 15) / 16, 256, 0, stream>>>(h2, csr, offs, dinv, b2, out, N);
}

// Round 4
// 323.518 us; speedup vs baseline: 7.0709x; 1.1169x over previous
//
#include <hip/hip_runtime.h>

// ---------------------------------------------------------------------------
// GCN encoder: out = GCNConv2( relu(GCNConv1(x)) )
// R3: GEMM restructured — LDS-staged A (coalesced, double-buffered),
// BM=128 with 2 row-tiles/wave for B-fragment reuse. Gathers unchanged.
// ---------------------------------------------------------------------------

typedef __attribute__((ext_vector_type(8))) short short8;
typedef __attribute__((ext_vector_type(4))) float floatx4;

// edge_index may arrive as int64 (reference dtype) or int32 (harness contract).
__global__ void detect64_kernel(const int* __restrict__ ei, int* __restrict__ flag) {
    __shared__ int nz;
    if (threadIdx.x == 0) nz = 0;
    __syncthreads();
    if (ei[2 * threadIdx.x + 1] != 0) atomicOr(&nz, 1);
    __syncthreads();
    if (threadIdx.x == 0) *flag = (nz == 0) ? 1 : 0;
}

__device__ __forceinline__ int edge_id(const int* __restrict__ ei, int is64, long long pos) {
    return is64 ? ei[2 * pos] : ei[(int)pos];
}

__global__ void count_deg_kernel(const int* __restrict__ ei, const int* __restrict__ flag,
                                 int* __restrict__ degi, int E) {
    int e = blockIdx.x * blockDim.x + threadIdx.x;
    if (e >= E) return;
    int is64 = *flag;
    int d = edge_id(ei, is64, (long long)E + e);
    atomicAdd(&degi[d], 1);
}

__global__ void dinv_kernel(const int* __restrict__ degi, float* __restrict__ dinv, int N) {
    int n = blockIdx.x * blockDim.x + threadIdx.x;
    if (n < N) dinv[n] = rsqrtf(1.0f + (float)degi[n]);
}

// ---------------- multi-block exclusive scan: degi[N] -> offs[N+1] ----------
__global__ void blocksum_kernel(const int* __restrict__ degi, int* __restrict__ bsum, int N) {
    __shared__ int sm[256];
    int t = threadIdx.x;
    int idx = blockIdx.x * 256 + t;
    sm[t] = (idx < N) ? degi[idx] : 0;
    __syncthreads();
    for (int s = 128; s > 0; s >>= 1) {
        if (t < s) sm[t] += sm[t + s];
        __syncthreads();
    }
    if (t == 0) bsum[blockIdx.x] = sm[0];
}

__global__ void scanb_kernel(int* __restrict__ bsum, int nb) {
    __shared__ int sm[256];
    int t = threadIdx.x;
    int v = (t < nb) ? bsum[t] : 0;
    sm[t] = v;
    __syncthreads();
    for (int s = 1; s < 256; s <<= 1) {
        int u = (t >= s) ? sm[t - s] : 0;
        __syncthreads();
        sm[t] += u;
        __syncthreads();
    }
    if (t < nb) bsum[t] = sm[t] - v;   // exclusive
}

__global__ void writeoffs_kernel(const int* __restrict__ degi, const int* __restrict__ bsum,
                                 int* __restrict__ offs, int N) {
    __shared__ int sm[256];
    int t = threadIdx.x;
    int idx = blockIdx.x * 256 + t;
    int v = (idx < N) ? degi[idx] : 0;
    sm[t] = v;
    __syncthreads();
    for (int s = 1; s < 256; s <<= 1) {
        int u = (t >= s) ? sm[t - s] : 0;
        __syncthreads();
        sm[t] += u;
        __syncthreads();
    }
    int incl = sm[t];
    int base = bsum[blockIdx.x];
    if (idx < N) offs[idx] = base + incl - v;
    if (idx == N - 1) offs[N] = base + incl;
}

// scatter edges into CSR: csr[pos] = {src, w=dinv[src]*dinv[dst]}
__global__ void scatter_kernel(const int* __restrict__ ei, const int* __restrict__ flag,
                               const int* __restrict__ offs, int* __restrict__ cursor,
                               const float* __restrict__ dinv, int2* __restrict__ csr, int E) {
    int e = blockIdx.x * blockDim.x + threadIdx.x;
    if (e >= E) return;
    int is64 = *flag;
    int s = edge_id(ei, is64, e);
    int d = edge_id(ei, is64, (long long)E + e);
    float w = dinv[s] * dinv[d];
    int pos = offs[d] + atomicAdd(&cursor[d], 1);
    csr[pos] = make_int2(s, __float_as_int(w));
}

// ---------------------------------------------------------------------------
// Weight pre-transform: W[K][Nc] fp32 -> Wh_t/Wl_t [Nc][K] bf16 (split hi/lo)
// ---------------------------------------------------------------------------
__device__ __forceinline__ unsigned short bf16_rne(float x) {
    unsigned u = __float_as_uint(x);
    return (unsigned short)((u + 0x7fff + ((u >> 16) & 1)) >> 16);
}

__global__ void convW_kernel(const float* __restrict__ W, unsigned short* __restrict__ Ht,
                             unsigned short* __restrict__ Lt, int K, int Nc) {
    int idx = blockIdx.x * blockDim.x + threadIdx.x;
    if (idx >= K * Nc) return;
    int k = idx / Nc, n = idx % Nc;
    float a = W[idx];
    unsigned u = __float_as_uint(a);
    unsigned short hi = (unsigned short)(u >> 16);          // truncation
    float hf = __uint_as_float(u & 0xffff0000u);
    unsigned short lo = bf16_rne(a - hf);
    Ht[(long long)n * K + k] = hi;
    Lt[(long long)n * K + k] = lo;
}

// ---------------------------------------------------------------------------
// Split-bf16 MFMA GEMM: C[M,NCOL] = A[M,K]fp32 @ B[K,NCOL]fp32
// B pre-transposed/split as Bh,Bl [NCOL][K] bf16 (L2-resident, tiny).
// Block = 256 thr = 4 waves; BM=128 rows (each wave: 2 row-tiles of 16).
// A staged via LDS with coalesced float4 loads, double-buffered.
// ---------------------------------------------------------------------------
template <int NCOL, int K>
__launch_bounds__(256)
__global__ void mfma_gemm_kernel(const float* __restrict__ A,
                                 const unsigned short* __restrict__ Bh,
                                 const unsigned short* __restrict__ Bl,
                                 float* __restrict__ C, int M) {
    constexpr int NCB = NCOL / 16;   // 8 (GEMM1) or 4 (GEMM2)
    constexpr int BM  = 128;         // rows per block
    constexpr int RT  = 2;           // row-tiles per wave
    constexpr int AST = 36;          // LDS row stride in floats (144 B, 16B-mult)
    __shared__ float As[2][BM * AST];

    const int tid  = threadIdx.x;
    const int wave = tid >> 6;
    const int lane = tid & 63;
    const int n15  = lane & 15;
    const int q    = lane >> 4;      // 0..3 (k-subchunk)
    const int row0 = blockIdx.x * BM;

    floatx4 acc[RT][NCB];
#pragma unroll
    for (int r = 0; r < RT; ++r)
#pragma unroll
        for (int c = 0; c < NCB; ++c) acc[r][c] = (floatx4){0.f, 0.f, 0.f, 0.f};

    // cooperative coalesced stage of a BM x 32 fp32 chunk into As[buf]
    auto stage = [&](int buf, int kc) {
#pragma unroll
        for (int it = 0; it < BM * 8 / 256; ++it) {   // BM*32 floats = BM*8 float4
            int f  = it * 256 + tid;
            int r  = f >> 3;
            int c4 = (f & 7) * 4;
            int gr = row0 + r;
            if (gr >= M) gr = M - 1;
            float4 v = *(const float4*)&A[(long long)gr * K + kc + c4];
            *(float4*)&As[buf][r * AST + c4] = v;
        }
    };

    stage(0, 0);
    __syncthreads();

    int buf = 0;
    for (int kc = 0; kc < K; kc += 32, buf ^= 1) {
        if (kc + 32 < K) stage(buf ^ 1, kc + 32);

        // A fragments from LDS: row = wave*32 + rt*16 + n15, cols q*8..q*8+7
        short8 ah[RT], al[RT];
#pragma unroll
        for (int rt = 0; rt < RT; ++rt) {
            const float* p = &As[buf][(wave * 32 + rt * 16 + n15) * AST + q * 8];
            float4 a0 = *(const float4*)p;
            float4 a1 = *(const float4*)(p + 4);
            float av[8] = {a0.x, a0.y, a0.z, a0.w, a1.x, a1.y, a1.z, a1.w};
#pragma unroll
            for (int j = 0; j < 8; ++j) {
                unsigned u = __float_as_uint(av[j]);
                ah[rt][j] = (short)(u >> 16);
                float hf = __uint_as_float(u & 0xffff0000u);
                al[rt][j] = (short)bf16_rne(av[j] - hf);
            }
        }

#pragma unroll
        for (int cb = 0; cb < NCB; ++cb) {
            long long boff = (long long)(cb * 16 + n15) * K + kc + q * 8;
            short8 bh = *(const short8*)&Bh[boff];
            short8 bl = *(const short8*)&Bl[boff];
#pragma unroll
            for (int rt = 0; rt < RT; ++rt) {
                acc[rt][cb] = __builtin_amdgcn_mfma_f32_16x16x32_bf16(ah[rt], bh, acc[rt][cb], 0, 0, 0);
                acc[rt][cb] = __builtin_amdgcn_mfma_f32_16x16x32_bf16(al[rt], bh, acc[rt][cb], 0, 0, 0);
                acc[rt][cb] = __builtin_amdgcn_mfma_f32_16x16x32_bf16(ah[rt], bl, acc[rt][cb], 0, 0, 0);
            }
        }
        __syncthreads();
    }

    // C/D layout: col = cb*16 + n15, row-in-tile = q*4 + reg
#pragma unroll
    for (int rt = 0; rt < RT; ++rt) {
#pragma unroll
        for (int cb = 0; cb < NCB; ++cb) {
            int col = cb * 16 + n15;
#pragma unroll
            for (int r = 0; r < 4; ++r) {
                int gr = row0 + wave * 32 + rt * 16 + q * 4 + r;
                if (gr < M) C[(long long)gr * NCOL + col] = acc[rt][cb][r];
            }
        }
    }
}

// ---------------------------------------------------------------------------
// Gather aggregation, float4 per lane:
// out[n][:] = (h[n]*dinv[n]^2 + sum_e h[src]*w) + bias (, relu)
// ---------------------------------------------------------------------------
template <int F, int RELU>
__launch_bounds__(256)
__global__ void gather4_kernel(const float* __restrict__ h, const int2* __restrict__ csr,
                               const int* __restrict__ offs, const float* __restrict__ dinv,
                               const float* __restrict__ bias, float* __restrict__ out, int N) {
    constexpr int L = F / 4;            // lanes per node
    constexpr int NPB = 256 / L;        // nodes per block
    const int n = blockIdx.x * NPB + threadIdx.x / L;
    const int c4 = (threadIdx.x % L) * 4;
    if (n >= N) return;
    const float di = dinv[n];
    float4 acc = *(const float4*)&h[(long long)n * F + c4];
    float sd = di * di;
    acc.x *= sd; acc.y *= sd; acc.z *= sd; acc.w *= sd;

    int j = offs[n];
    const int end = offs[n + 1];
    for (; j + 3 < end; j += 4) {
        int2 e0 = csr[j], e1 = csr[j + 1], e2 = csr[j + 2], e3 = csr[j + 3];
        float4 v0 = *(const float4*)&h[(long long)e0.x * F + c4];
        float4 v1 = *(const float4*)&h[(long long)e1.x * F + c4];
        float4 v2 = *(const float4*)&h[(long long)e2.x * F + c4];
        float4 v3 = *(const float4*)&h[(long long)e3.x * F + c4];
        float w0 = __int_as_float(e0.y), w1 = __int_as_float(e1.y);
        float w2 = __int_as_float(e2.y), w3 = __int_as_float(e3.y);
        acc.x = fmaf(v0.x, w0, acc.x); acc.y = fmaf(v0.y, w0, acc.y);
        acc.z = fmaf(v0.z, w0, acc.z); acc.w = fmaf(v0.w, w0, acc.w);
        acc.x = fmaf(v1.x, w1, acc.x); acc.y = fmaf(v1.y, w1, acc.y);
        acc.z = fmaf(v1.z, w1, acc.z); acc.w = fmaf(v1.w, w1, acc.w);
        acc.x = fmaf(v2.x, w2, acc.x); acc.y = fmaf(v2.y, w2, acc.y);
        acc.z = fmaf(v2.z, w2, acc.z); acc.w = fmaf(v2.w, w2, acc.w);
        acc.x = fmaf(v3.x, w3, acc.x); acc.y = fmaf(v3.y, w3, acc.y);
        acc.z = fmaf(v3.z, w3, acc.z); acc.w = fmaf(v3.w, w3, acc.w);
    }
    for (; j < end; ++j) {
        int2 e = csr[j];
        float w = __int_as_float(e.y);
        float4 v = *(const float4*)&h[(long long)e.x * F + c4];
        acc.x = fmaf(v.x, w, acc.x); acc.y = fmaf(v.y, w, acc.y);
        acc.z = fmaf(v.z, w, acc.z); acc.w = fmaf(v.w, w, acc.w);
    }
    float4 b = *(const float4*)&bias[c4];
    acc.x += b.x; acc.y += b.y; acc.z += b.z; acc.w += b.w;
    if (RELU) {
        acc.x = fmaxf(acc.x, 0.f); acc.y = fmaxf(acc.y, 0.f);
        acc.z = fmaxf(acc.z, 0.f); acc.w = fmaxf(acc.w, 0.f);
    }
    *(float4*)&out[(long long)n * F + c4] = acc;
}

extern "C" void kernel_launch(void* const* d_in, const int* in_sizes, int n_in,
                              void* d_out, int out_size, void* d_ws, size_t ws_size,
                              hipStream_t stream) {
    const float* x  = (const float*)d_in[0];
    const int*   ei = (const int*)d_in[1];
    const float* W1 = (const float*)d_in[2];
    const float* b1 = (const float*)d_in[3];
    const float* W2 = (const float*)d_in[4];
    const float* b2 = (const float*)d_in[5];
    float* out = (float*)d_out;

    const int IN_CH = 256, HID = 128, OUT = 64;
    const int N = in_sizes[0] / IN_CH;     // 50000
    const int E = in_sizes[1] / 2;         // 800000

    char* w = (char*)d_ws;
    size_t off_b = 0;
    auto alloc = [&](size_t bytes) { void* p = w + off_b; off_b = (off_b + bytes + 255) & ~(size_t)255; return p; };
    int*   flag   = (int*)alloc(256);
    int*   degi   = (int*)alloc((size_t)N * 4);
    int*   offs   = (int*)alloc((size_t)(N + 1) * 4);
    int*   cursor = (int*)alloc((size_t)N * 4);
    float* dinv   = (float*)alloc((size_t)N * 4);
    int*   bsum   = (int*)alloc(256 * 4);
    int2*  csr    = (int2*)alloc((size_t)E * 8);
    unsigned short* W1h = (unsigned short*)alloc((size_t)IN_CH * HID * 2);
    unsigned short* W1l = (unsigned short*)alloc((size_t)IN_CH * HID * 2);
    unsigned short* W2h = (unsigned short*)alloc((size_t)HID * OUT * 2);
    unsigned short* W2l = (unsigned short*)alloc((size_t)HID * OUT * 2);
    float* h1     = (float*)alloc((size_t)N * HID * 4);    // reused as h2
    float* agg1   = (float*)alloc((size_t)N * HID * 4);
    float* h2     = h1;

    hipMemsetAsync(degi,   0, (size_t)N * 4, stream);
    hipMemsetAsync(cursor, 0, (size_t)N * 4, stream);

    const int T = 256;
    const int nb = (N + 255) / 256;
    detect64_kernel<<<1, 256, 0, stream>>>(ei, flag);
    count_deg_kernel<<<(E + T - 1) / T, T, 0, stream>>>(ei, flag, degi, E);
    dinv_kernel<<<(N + T - 1) / T, T, 0, stream>>>(degi, dinv, N);
    blocksum_kernel<<<nb, 256, 0, stream>>>(degi, bsum, N);
    scanb_kernel<<<1, 256, 0, stream>>>(bsum, nb);
    writeoffs_kernel<<<nb, 256, 0, stream>>>(degi, bsum, offs, N);
    scatter_kernel<<<(E + T - 1) / T, T, 0, stream>>>(ei, flag, offs, cursor, dinv, csr, E);

    convW_kernel<<<(IN_CH * HID + T - 1) / T, T, 0, stream>>>(W1, W1h, W1l, IN_CH, HID);
    convW_kernel<<<(HID * OUT + T - 1) / T, T, 0, stream>>>(W2, W2h, W2l, HID, OUT);

    // GEMM1: h1[N,128] = x[N,256] @ W1
    mfma_gemm_kernel<128, 256><<<(N + 127) / 128, 256, 0, stream>>>(x, W1h, W1l, h1, N);
    // layer-1 aggregation (gather, fused self-loop + bias + relu) -> agg1
    gather4_kernel<128, 1><<<(N + 7) / 8, 256, 0, stream>>>(h1, csr, offs, dinv, b1, agg1, N);
    // GEMM2: h2[N,64] = agg1[N,128] @ W2
    mfma_gemm_kernel<64, 128><<<(N + 127) / 128, 256, 0, stream>>>(agg1, W2h, W2l, h2, N);
    // layer-2 aggregation (gather, fused self-loop + bias) -> out
    gather4_kernel<64, 0><<<(N + 15) / 16, 256, 0, stream>>>(h2, csr, offs, dinv, b2, out, N);
}

// Round 5
// 287.548 us; speedup vs baseline: 7.9554x; 1.1251x over previous
//
#include <hip/hip_runtime.h>

// ---------------------------------------------------------------------------
// GCN encoder: out = GCNConv2( relu(GCNConv1(x)) )
// R4: h1/h2 stored fp16 (halves gather traffic + L2 footprint), agg1 fp32.
// Gather unrolled x8. Fewer dispatches (fused dinv, single convW, 1 memset).
// ---------------------------------------------------------------------------

typedef __attribute__((ext_vector_type(8))) short short8;
typedef __attribute__((ext_vector_type(4))) float floatx4;
typedef _Float16 __attribute__((ext_vector_type(8))) half8v;

// edge_index may arrive as int64 (reference dtype) or int32 (harness contract).
__global__ void detect64_kernel(const int* __restrict__ ei, int* __restrict__ flag) {
    __shared__ int nz;
    if (threadIdx.x == 0) nz = 0;
    __syncthreads();
    if (ei[2 * threadIdx.x + 1] != 0) atomicOr(&nz, 1);
    __syncthreads();
    if (threadIdx.x == 0) *flag = (nz == 0) ? 1 : 0;
}

__device__ __forceinline__ int edge_id(const int* __restrict__ ei, int is64, long long pos) {
    return is64 ? ei[2 * pos] : ei[(int)pos];
}

__global__ void count_deg_kernel(const int* __restrict__ ei, const int* __restrict__ flag,
                                 int* __restrict__ degi, int E) {
    int e = blockIdx.x * blockDim.x + threadIdx.x;
    if (e >= E) return;
    int is64 = *flag;
    int d = edge_id(ei, is64, (long long)E + e);
    atomicAdd(&degi[d], 1);
}

// ---------------- multi-block exclusive scan: degi[N] -> offs[N+1] ----------
__global__ void blocksum_kernel(const int* __restrict__ degi, int* __restrict__ bsum, int N) {
    __shared__ int sm[256];
    int t = threadIdx.x;
    int idx = blockIdx.x * 256 + t;
    sm[t] = (idx < N) ? degi[idx] : 0;
    __syncthreads();
    for (int s = 128; s > 0; s >>= 1) {
        if (t < s) sm[t] += sm[t + s];
        __syncthreads();
    }
    if (t == 0) bsum[blockIdx.x] = sm[0];
}

__global__ void scanb_kernel(int* __restrict__ bsum, int nb) {
    __shared__ int sm[256];
    int t = threadIdx.x;
    int v = (t < nb) ? bsum[t] : 0;
    sm[t] = v;
    __syncthreads();
    for (int s = 1; s < 256; s <<= 1) {
        int u = (t >= s) ? sm[t - s] : 0;
        __syncthreads();
        sm[t] += u;
        __syncthreads();
    }
    if (t < nb) bsum[t] = sm[t] - v;   // exclusive
}

// also computes dinv[n] = rsqrt(1 + deg[n]) (fused)
__global__ void writeoffs_kernel(const int* __restrict__ degi, const int* __restrict__ bsum,
                                 int* __restrict__ offs, float* __restrict__ dinv, int N) {
    __shared__ int sm[256];
    int t = threadIdx.x;
    int idx = blockIdx.x * 256 + t;
    int v = (idx < N) ? degi[idx] : 0;
    sm[t] = v;
    __syncthreads();
    for (int s = 1; s < 256; s <<= 1) {
        int u = (t >= s) ? sm[t - s] : 0;
        __syncthreads();
        sm[t] += u;
        __syncthreads();
    }
    int incl = sm[t];
    int base = bsum[blockIdx.x];
    if (idx < N) {
        offs[idx] = base + incl - v;
        dinv[idx] = rsqrtf(1.0f + (float)v);
    }
    if (idx == N - 1) offs[N] = base + incl;
}

// scatter edges into CSR: csr[pos] = {src, w=dinv[src]*dinv[dst]}
__global__ void scatter_kernel(const int* __restrict__ ei, const int* __restrict__ flag,
                               const int* __restrict__ offs, int* __restrict__ cursor,
                               const float* __restrict__ dinv, int2* __restrict__ csr, int E) {
    int e = blockIdx.x * blockDim.x + threadIdx.x;
    if (e >= E) return;
    int is64 = *flag;
    int s = edge_id(ei, is64, e);
    int d = edge_id(ei, is64, (long long)E + e);
    float w = dinv[s] * dinv[d];
    int pos = offs[d] + atomicAdd(&cursor[d], 1);
    csr[pos] = make_int2(s, __float_as_int(w));
}

// ---------------------------------------------------------------------------
// Weight pre-transform: W[K][Nc] fp32 -> Wh_t/Wl_t [Nc][K] bf16 (split hi/lo)
// One launch handles both weight matrices (blockIdx partition).
// ---------------------------------------------------------------------------
__device__ __forceinline__ unsigned short bf16_rne(float x) {
    unsigned u = __float_as_uint(x);
    return (unsigned short)((u + 0x7fff + ((u >> 16) & 1)) >> 16);
}

__device__ __forceinline__ void convW_one(const float* W, unsigned short* Ht,
                                          unsigned short* Lt, int K, int Nc, int idx) {
    if (idx >= K * Nc) return;
    int k = idx / Nc, n = idx % Nc;
    float a = W[idx];
    unsigned u = __float_as_uint(a);
    unsigned short hi = (unsigned short)(u >> 16);          // truncation
    float hf = __uint_as_float(u & 0xffff0000u);
    unsigned short lo = bf16_rne(a - hf);
    Ht[(long long)n * K + k] = hi;
    Lt[(long long)n * K + k] = lo;
}

__global__ void convW_kernel(const float* __restrict__ W1, unsigned short* __restrict__ H1,
                             unsigned short* __restrict__ L1, int K1, int N1, int nb1,
                             const float* __restrict__ W2, unsigned short* __restrict__ H2,
                             unsigned short* __restrict__ L2, int K2, int N2) {
    if ((int)blockIdx.x < nb1) {
        convW_one(W1, H1, L1, K1, N1, blockIdx.x * blockDim.x + threadIdx.x);
    } else {
        convW_one(W2, H2, L2, K2, N2, (blockIdx.x - nb1) * blockDim.x + threadIdx.x);
    }
}

// ---------------------------------------------------------------------------
// Split-bf16 MFMA GEMM: C[M,NCOL] = A[M,K]fp32 @ B[K,NCOL]fp32
// B pre-transposed/split as Bh,Bl [NCOL][K] bf16 (L2-resident, tiny).
// Block = 256 thr = 4 waves; BM=128 rows (each wave: 2 row-tiles of 16).
// A staged via LDS (coalesced float4, double-buffered). C written as CT.
// ---------------------------------------------------------------------------
template <int NCOL, int K, typename CT>
__launch_bounds__(256)
__global__ void mfma_gemm_kernel(const float* __restrict__ A,
                                 const unsigned short* __restrict__ Bh,
                                 const unsigned short* __restrict__ Bl,
                                 CT* __restrict__ C, int M) {
    constexpr int NCB = NCOL / 16;   // 8 (GEMM1) or 4 (GEMM2)
    constexpr int BM  = 128;
    constexpr int RT  = 2;
    constexpr int AST = 36;          // LDS row stride in floats
    __shared__ float As[2][BM * AST];

    const int tid  = threadIdx.x;
    const int wave = tid >> 6;
    const int lane = tid & 63;
    const int n15  = lane & 15;
    const int q    = lane >> 4;
    const int row0 = blockIdx.x * BM;

    floatx4 acc[RT][NCB];
#pragma unroll
    for (int r = 0; r < RT; ++r)
#pragma unroll
        for (int c = 0; c < NCB; ++c) acc[r][c] = (floatx4){0.f, 0.f, 0.f, 0.f};

    auto stage = [&](int buf, int kc) {
#pragma unroll
        for (int it = 0; it < BM * 8 / 256; ++it) {
            int f  = it * 256 + tid;
            int r  = f >> 3;
            int c4 = (f & 7) * 4;
            int gr = row0 + r;
            if (gr >= M) gr = M - 1;
            float4 v = *(const float4*)&A[(long long)gr * K + kc + c4];
            *(float4*)&As[buf][r * AST + c4] = v;
        }
    };

    stage(0, 0);
    __syncthreads();

    int buf = 0;
    for (int kc = 0; kc < K; kc += 32, buf ^= 1) {
        if (kc + 32 < K) stage(buf ^ 1, kc + 32);

        short8 ah[RT], al[RT];
#pragma unroll
        for (int rt = 0; rt < RT; ++rt) {
            const float* p = &As[buf][(wave * 32 + rt * 16 + n15) * AST + q * 8];
            float4 a0 = *(const float4*)p;
            float4 a1 = *(const float4*)(p + 4);
            float av[8] = {a0.x, a0.y, a0.z, a0.w, a1.x, a1.y, a1.z, a1.w};
#pragma unroll
            for (int j = 0; j < 8; ++j) {
                unsigned u = __float_as_uint(av[j]);
                ah[rt][j] = (short)(u >> 16);
                float hf = __uint_as_float(u & 0xffff0000u);
                al[rt][j] = (short)bf16_rne(av[j] - hf);
            }
        }

#pragma unroll
        for (int cb = 0; cb < NCB; ++cb) {
            long long boff = (long long)(cb * 16 + n15) * K + kc + q * 8;
            short8 bh = *(const short8*)&Bh[boff];
            short8 bl = *(const short8*)&Bl[boff];
#pragma unroll
            for (int rt = 0; rt < RT; ++rt) {
                acc[rt][cb] = __builtin_amdgcn_mfma_f32_16x16x32_bf16(ah[rt], bh, acc[rt][cb], 0, 0, 0);
                acc[rt][cb] = __builtin_amdgcn_mfma_f32_16x16x32_bf16(al[rt], bh, acc[rt][cb], 0, 0, 0);
                acc[rt][cb] = __builtin_amdgcn_mfma_f32_16x16x32_bf16(ah[rt], bl, acc[rt][cb], 0, 0, 0);
            }
        }
        __syncthreads();
    }

    // C/D layout: col = cb*16 + n15, row-in-tile = q*4 + reg
#pragma unroll
    for (int rt = 0; rt < RT; ++rt) {
#pragma unroll
        for (int cb = 0; cb < NCB; ++cb) {
            int col = cb * 16 + n15;
#pragma unroll
            for (int r = 0; r < 4; ++r) {
                int gr = row0 + wave * 32 + rt * 16 + q * 4 + r;
                if (gr < M) C[(long long)gr * NCOL + col] = (CT)acc[rt][cb][r];
            }
        }
    }
}

// ---------------------------------------------------------------------------
// Gather aggregation, fp16 h, 8 channels/lane, 8-edge unroll:
// out[n][:] = (h[n]*dinv[n]^2 + sum_e h[src]*w) + bias (, relu)   [out fp32]
// ---------------------------------------------------------------------------
template <int F, int RELU>
__launch_bounds__(256)
__global__ void gatherh_kernel(const _Float16* __restrict__ h, const int2* __restrict__ csr,
                               const int* __restrict__ offs, const float* __restrict__ dinv,
                               const float* __restrict__ bias, float* __restrict__ out, int N) {
    constexpr int L = F / 8;            // lanes per node
    constexpr int NPB = 256 / L;        // nodes per block
    const int n = blockIdx.x * NPB + threadIdx.x / L;
    const int c8 = (threadIdx.x % L) * 8;
    if (n >= N) return;

    const float di = dinv[n];
    const float sd = di * di;
    half8v hs = *(const half8v*)&h[(long long)n * F + c8];
    float acc[8];
#pragma unroll
    for (int j = 0; j < 8; ++j) acc[j] = (float)hs[j] * sd;

    int j = offs[n];
    const int end = offs[n + 1];
    for (; j + 7 < end; j += 8) {
        int2 e[8];
        half8v v[8];
#pragma unroll
        for (int u = 0; u < 8; ++u) e[u] = csr[j + u];
#pragma unroll
        for (int u = 0; u < 8; ++u) v[u] = *(const half8v*)&h[(long long)e[u].x * F + c8];
#pragma unroll
        for (int u = 0; u < 8; ++u) {
            float w = __int_as_float(e[u].y);
#pragma unroll
            for (int t = 0; t < 8; ++t) acc[t] = fmaf((float)v[u][t], w, acc[t]);
        }
    }
    for (; j < end; ++j) {
        int2 e = csr[j];
        float w = __int_as_float(e.y);
        half8v v = *(const half8v*)&h[(long long)e.x * F + c8];
#pragma unroll
        for (int t = 0; t < 8; ++t) acc[t] = fmaf((float)v[t], w, acc[t]);
    }

    float4 b0 = *(const float4*)&bias[c8];
    float4 b1 = *(const float4*)&bias[c8 + 4];
    float bb[8] = {b0.x, b0.y, b0.z, b0.w, b1.x, b1.y, b1.z, b1.w};
#pragma unroll
    for (int t = 0; t < 8; ++t) {
        acc[t] += bb[t];
        if (RELU) acc[t] = fmaxf(acc[t], 0.f);
    }
    float* o = &out[(long long)n * F + c8];
    *(float4*)o       = make_float4(acc[0], acc[1], acc[2], acc[3]);
    *(float4*)(o + 4) = make_float4(acc[4], acc[5], acc[6], acc[7]);
}

extern "C" void kernel_launch(void* const* d_in, const int* in_sizes, int n_in,
                              void* d_out, int out_size, void* d_ws, size_t ws_size,
                              hipStream_t stream) {
    const float* x  = (const float*)d_in[0];
    const int*   ei = (const int*)d_in[1];
    const float* W1 = (const float*)d_in[2];
    const float* b1 = (const float*)d_in[3];
    const float* W2 = (const float*)d_in[4];
    const float* b2 = (const float*)d_in[5];
    float* out = (float*)d_out;

    const int IN_CH = 256, HID = 128, OUT = 64;
    const int N = in_sizes[0] / IN_CH;     // 50000
    const int E = in_sizes[1] / 2;         // 800000

    char* w = (char*)d_ws;
    size_t off_b = 0;
    auto alloc = [&](size_t bytes) { void* p = w + off_b; off_b = (off_b + bytes + 255) & ~(size_t)255; return p; };
    int*   flag   = (int*)alloc(256);
    int*   degi   = (int*)alloc((size_t)2 * N * 4);        // degi[N] + cursor[N], one memset
    int*   cursor = degi + N;
    int*   offs   = (int*)alloc((size_t)(N + 1) * 4);
    float* dinv   = (float*)alloc((size_t)N * 4);
    int*   bsum   = (int*)alloc(256 * 4);
    int2*  csr    = (int2*)alloc((size_t)E * 8);
    unsigned short* W1h = (unsigned short*)alloc((size_t)IN_CH * HID * 2);
    unsigned short* W1l = (unsigned short*)alloc((size_t)IN_CH * HID * 2);
    unsigned short* W2h = (unsigned short*)alloc((size_t)HID * OUT * 2);
    unsigned short* W2l = (unsigned short*)alloc((size_t)HID * OUT * 2);
    _Float16* h1  = (_Float16*)alloc((size_t)N * HID * 2); // fp16; reused as h2
    float* agg1   = (float*)alloc((size_t)N * HID * 4);    // fp32
    _Float16* h2  = h1;

    hipMemsetAsync(degi, 0, (size_t)2 * N * 4, stream);

    const int T = 256;
    const int nb = (N + 255) / 256;
    detect64_kernel<<<1, 256, 0, stream>>>(ei, flag);
    count_deg_kernel<<<(E + T - 1) / T, T, 0, stream>>>(ei, flag, degi, E);
    blocksum_kernel<<<nb, 256, 0, stream>>>(degi, bsum, N);
    scanb_kernel<<<1, 256, 0, stream>>>(bsum, nb);
    writeoffs_kernel<<<nb, 256, 0, stream>>>(degi, bsum, offs, dinv, N);
    scatter_kernel<<<(E + T - 1) / T, T, 0, stream>>>(ei, flag, offs, cursor, dinv, csr, E);

    {
        int nb1 = (IN_CH * HID + T - 1) / T;
        int nb2 = (HID * OUT + T - 1) / T;
        convW_kernel<<<nb1 + nb2, T, 0, stream>>>(W1, W1h, W1l, IN_CH, HID, nb1,
                                                  W2, W2h, W2l, HID, OUT);
    }

    // GEMM1: h1[N,128](fp16) = x[N,256] @ W1
    mfma_gemm_kernel<128, 256, _Float16><<<(N + 127) / 128, 256, 0, stream>>>(x, W1h, W1l, h1, N);
    // layer-1 aggregation (fp16 gather, fused self-loop + bias + relu) -> agg1 (fp32)
    gatherh_kernel<128, 1><<<(N * 16 + 255) / 256, 256, 0, stream>>>(h1, csr, offs, dinv, b1, agg1, N);
    // GEMM2: h2[N,64](fp16) = agg1[N,128] @ W2
    mfma_gemm_kernel<64, 128, _Float16><<<(N + 127) / 128, 256, 0, stream>>>(agg1, W2h, W2l, h2, N);
    // layer-2 aggregation (fp16 gather, fused self-loop + bias) -> out (fp32)
    gatherh_kernel<64, 0><<<(N * 8 + 255) / 256, 256, 0, stream>>>(h2, csr, offs, dinv, b2, out, N);
}